// Round 5
// baseline (924.461 us; speedup 1.0000x reference)
//
#include <hip/hip_runtime.h>
#include <hip/hip_bf16.h>

// PolyAttentionBlock: B=16 N=1024 C=768 H=12 D=64. attn = a*s^2+b*s+c (no softmax).
// cvt(f32->bf16) -> QK GEMM + V GEMM (256^2 BK=32 8-phase, 2 blocks/CU) -> poly-attn -> proj GEMM.

typedef float  f32x4  __attribute__((ext_vector_type(4)));
typedef __bf16 bf16x8 __attribute__((ext_vector_type(8)));
typedef __bf16 bf16x4 __attribute__((ext_vector_type(4)));

#define AS1 __attribute__((address_space(1)))
#define AS3 __attribute__((address_space(3)))

__device__ __forceinline__ void gl16(const void* g, void* l) {
  // async global->LDS, 16B/lane; LDS dest = wave-uniform base + lane*16
  __builtin_amdgcn_global_load_lds((const AS1 unsigned int*)g, (AS3 unsigned int*)l, 16, 0, 0);
}

// ---------------- f32 -> bf16 cast ----------------
__global__ __launch_bounds__(256) void cvtk(const float* __restrict__ s,
                                            __bf16* __restrict__ d, int n) {
  int i = (blockIdx.x * 256 + threadIdx.x) * 4;
  if (i >= n) return;
  float4 v = *reinterpret_cast<const float4*>(s + i);
  bf16x4 o = { (__bf16)v.x, (__bf16)v.y, (__bf16)v.z, (__bf16)v.w };
  *reinterpret_cast<bf16x4*>(d + i) = o;
}

// ---------------- 256x256 BK=32 8-phase GEMM: out = A[M,K] @ W[Nn,K]^T + bias ----------------
// 512 thr = 8 waves (2M x 4N). LDS 64KB (2 dbuf x (A 16KB + B 16KB)) -> 2 blocks/CU.
// LDS layout: 16 chunks of 1KB per tile; within chunk k-major (slot = kunit*16 + row%16)
// realized via per-lane global src permutation -> conflict-free 256B-contiguous ds_read_b128.
// Schedule: 1 gl16/phase; gates vmcnt(3) at ph4/ph8 (vmcnt(0) last-iter ph4).
// SWAP=1: mfma(B,A) -> D^T fragments -> packed col-run stores (bf16x4 / f32x4).
// SWAP=0: mfma(A,B) -> row-run fragments -> V written transposed into vout[B,H,64,1024].
template <int MODE, bool SWAP>  // MODE 0: bf16 out, 1: f32 out
__global__ __launch_bounds__(512, 4) void gemm256k(
    const __bf16* __restrict__ A, const __bf16* __restrict__ W,
    const float* __restrict__ bias, void* __restrict__ outp,
    __bf16* __restrict__ vout, int K, int nby, int chunk, int col_base, int ldo) {
  __shared__ char lds[65536];  // buf b: A @ b*32768, B @ b*32768+16384
  const int t = threadIdx.x, w = t >> 6, l = t & 63;
  const int l15 = l & 15, lg = l >> 4;
  const int wm = w >> 2, wn = w & 3;  // wave grid 2x4; wave tile 128r x 64c

  // bijective XCD-chunked swizzle (nblocks % 8 == 0); row-major chunks
  const int fid = blockIdx.x;
  const int logical = (fid & 7) * chunk + (fid >> 3);
  const int bx = logical / nby, by = logical % nby;
  const int row0 = bx * 256, col0 = col_base + by * 256;

  const f32x4 zz = {0.f, 0.f, 0.f, 0.f};
  f32x4 acc[8][4];
#pragma unroll
  for (int m = 0; m < 8; ++m)
#pragma unroll
    for (int n = 0; n < 4; ++n) acc[m][n] = zz;
  bf16x8 af[2], bfr[4];

// stage A half H (H=0: chunks {0-3,8-11} = m-quarters 0,1; H=1: {4-7,12-15} = mq 2,3)
// chunk c rows = c*16..c*16+15; lane l -> logical (row = c*16 + l15, kunit = lg)
#define STA(BUF, H, KT)                                                         \
  do {                                                                          \
    const int c_ = (H)*4 + (w & 3) + (w >> 2) * 8;                              \
    gl16(A + (size_t)(row0 + c_ * 16 + l15) * K + (KT)*32 + lg * 8,             \
         lds + (BUF)*32768 + c_ * 1024);                                        \
  } while (0)
// stage B half H (chunks H*8+w)
#define STB(BUF, H, KT)                                                         \
  do {                                                                          \
    const int c_ = (H)*8 + w;                                                   \
    gl16(W + (size_t)(col0 + c_ * 16 + l15) * K + (KT)*32 + lg * 8,             \
         lds + (BUF)*32768 + 16384 + c_ * 1024);                                \
  } while (0)
// ds-read A-frags for m-quarter MQ (chunks wm*8 + 2MQ+j) -- 256B-contiguous per 16 lanes
#define RDA(BUF, MQ)                                                            \
  do {                                                                          \
    _Pragma("unroll") for (int j = 0; j < 2; ++j)                               \
        af[j] = *(const bf16x8*)(lds + (BUF)*32768 +                            \
                                 (wm * 8 + 2 * (MQ) + j) * 1024 + lg * 256 +    \
                                 l15 * 16);                                     \
  } while (0)
// ds-read all B-frags (chunks wn*4+n)
#define RDB(BUF)                                                                \
  do {                                                                          \
    _Pragma("unroll") for (int n = 0; n < 4; ++n)                               \
        bfr[n] = *(const bf16x8*)(lds + (BUF)*32768 + 16384 +                   \
                                  (wn * 4 + n) * 1024 + lg * 256 + l15 * 16);   \
  } while (0)
#define MF8(MQ)                                                                 \
  do {                                                                          \
    __builtin_amdgcn_s_setprio(1);                                              \
    _Pragma("unroll") for (int j = 0; j < 2; ++j)                               \
        _Pragma("unroll") for (int n = 0; n < 4; ++n) {                         \
      if (SWAP)                                                                 \
        acc[2 * (MQ) + j][n] = __builtin_amdgcn_mfma_f32_16x16x32_bf16(         \
            bfr[n], af[j], acc[2 * (MQ) + j][n], 0, 0, 0);                      \
      else                                                                      \
        acc[2 * (MQ) + j][n] = __builtin_amdgcn_mfma_f32_16x16x32_bf16(         \
            af[j], bfr[n], acc[2 * (MQ) + j][n], 0, 0, 0);                      \
    }                                                                           \
    __builtin_amdgcn_s_setprio(0);                                              \
  } while (0)
#define BAR1 __builtin_amdgcn_s_barrier(); asm volatile("s_waitcnt lgkmcnt(0)" ::: "memory")
#define BAR2 __builtin_amdgcn_s_barrier()
#define GATE(N) asm volatile("s_waitcnt vmcnt(" #N ")" ::: "memory")

  // prologue: K-tile 0 full (4 loads) -> buf0; K-tile 1 partial (3) -> buf1
  STA(0, 0, 0); STA(0, 1, 0); STB(0, 0, 0); STB(0, 1, 0);
  STA(1, 0, 1); STB(1, 0, 1); STB(1, 1, 1);
  GATE(3);
  BAR2;

  const int NI = K >> 6;  // 2 K-tiles (BK=32) per iteration
  for (int i = 0; i < NI; ++i) {
    const bool last = (i == NI - 1);
    const int t1 = 2 * i + 1, t2 = 2 * i + 2, t3 = 2 * i + 3;
    // ph1 (buf0 mq0): finish buf1 A (h1 = mq2/3, read last at prev ph8)
    RDA(0, 0); RDB(0);
    STA(1, 1, t1);
    BAR1; MF8(0); BAR2;
    // ph2: B-buf0 fully read in ph1 -> refill B h0
    RDA(0, 1);
    if (!last) STB(0, 0, t2);
    BAR1; MF8(1); BAR2;
    // ph3: A-buf0 mq0/1 read -> refill A h0
    RDA(0, 2);
    if (!last) STA(0, 0, t2);
    BAR1; MF8(2); BAR2;
    // ph4 + gate (buf1 = t1 must be complete for ph5)
    RDA(0, 3);
    if (!last) STB(0, 1, t2);
    if (last) { GATE(0); } else { GATE(3); }
    BAR1; MF8(3); BAR2;
    // ph5 (buf1 mq0): A-buf0 mq2/3 read in ph3/4 -> refill A h1
    RDA(1, 0); RDB(1);
    if (!last) STA(0, 1, t2);
    BAR1; MF8(0); BAR2;
    // ph6
    RDA(1, 1);
    if (!last) STB(1, 0, t3);
    BAR1; MF8(1); BAR2;
    // ph7
    RDA(1, 2);
    if (!last) STA(1, 0, t3);
    BAR1; MF8(2); BAR2;
    // ph8 + gate (buf0 = t2 must be complete for next ph1)
    RDA(1, 3);
    if (!last) STB(1, 1, t3);
    if (!last) { GATE(3); }
    BAR1; MF8(3); BAR2;
  }

  // ---------------- epilogue ----------------
  if (SWAP) {
    // D^T frags: row = wm*128 + m*16 + l15 ; cols = col0 + wn*64 + n*16 + lg*4 + e
    f32x4 bv4[4];
#pragma unroll
    for (int n = 0; n < 4; ++n)
      bv4[n] = *(const f32x4*)(bias + col0 + wn * 64 + n * 16 + lg * 4);
#pragma unroll
    for (int m = 0; m < 8; ++m) {
      const int row = row0 + wm * 128 + m * 16 + l15;
#pragma unroll
      for (int n = 0; n < 4; ++n) {
        const int colb = col0 + wn * 64 + n * 16 + lg * 4;
        if (MODE == 0) {
          bf16x4 pk;
#pragma unroll
          for (int e = 0; e < 4; ++e) pk[e] = (__bf16)(acc[m][n][e] + bv4[n][e]);
          *(bf16x4*)((__bf16*)outp + (size_t)row * ldo + colb) = pk;
        } else {
          f32x4 v;
#pragma unroll
          for (int e = 0; e < 4; ++e) v[e] = acc[m][n][e] + bv4[n][e];
          *(f32x4*)((float*)outp + (size_t)row * ldo + colb) = v;
        }
      }
    }
  } else {
    // V path: rows run along e -> contiguous nn in vout[B,H,64,1024]
    float bv[4];
#pragma unroll
    for (int n = 0; n < 4; ++n) bv[n] = bias[col0 + wn * 64 + n * 16 + l15];
#pragma unroll
    for (int m = 0; m < 8; ++m)
#pragma unroll
      for (int n = 0; n < 4; ++n) {
        const int cv = col0 + wn * 64 + n * 16 + l15 - 1536;
        const int h = cv >> 6, d = cv & 63;
        const int row = row0 + wm * 128 + m * 16 + lg * 4;
        const int b = row >> 10, nn = row & 1023;
        bf16x4 pk;
#pragma unroll
        for (int e = 0; e < 4; ++e) pk[e] = (__bf16)(acc[m][n][e] + bv[n]);
        *(bf16x4*)(vout + (((size_t)(b * 12 + h)) << 16) + (d << 10) + nn) = pk;
      }
  }
#undef STA
#undef STB
#undef RDA
#undef RDB
#undef MF8
#undef BAR1
#undef BAR2
#undef GATE
}

// ---------------- fused poly attention ----------------
// grid 1536 blocks (XCD-chunked swizzle), 256 thr = 4 waves; KVBLK=64, 16 tiles.
// Swapped QK^T -> per-thread consecutive-m P -> packed bf16x4 ds_write into per-wave lP.
__global__ __launch_bounds__(256, 3) void attnk(const __bf16* __restrict__ qkv,
                                                const __bf16* __restrict__ vT,
                                                __bf16* __restrict__ o,
                                                const float* __restrict__ poly) {
  __shared__ __bf16 lK[64 * 64];   // 8KB  [m][d=64], 128B rows, XOR-swizzled
  __shared__ __bf16 lV[64 * 64];   // 8KB  [d][m=64], 128B rows, XOR-swizzled
  __shared__ __bf16 lP[128 * 64];  // 16KB [q][m=64], 128B rows, XOR-swizzled; wave w owns rows w*32..+31
  const int t = threadIdx.x, w = t >> 6, l = t & 63;
  const int l15 = l & 15, lg = l >> 4;

  const int fid = blockIdx.y * 8 + blockIdx.x;       // 0..1535
  const int logical = (fid & 7) * 192 + (fid >> 3);
  const int bh = logical >> 3, q0 = (logical & 7) * 128;
  const int b = bh / 12, h = bh - b * 12;
  const float pa = poly[0], pb = poly[1], pc = poly[2];
  const f32x4 zz = {0.f, 0.f, 0.f, 0.f};

  bf16x8 qf[2][2];
#pragma unroll
  for (int a = 0; a < 2; ++a)
#pragma unroll
    for (int kk = 0; kk < 2; ++kk)
      qf[a][kk] = *(const bf16x8*)(qkv + (size_t)(b * 1024 + q0 + w * 32 + 16 * a + l15) * 2304 +
                                   h * 64 + kk * 32 + lg * 8);

  f32x4 oacc[2][4];
#pragma unroll
  for (int mf = 0; mf < 2; ++mf)
#pragma unroll
    for (int n = 0; n < 4; ++n) oacc[mf][n] = zz;

  const int srow = l >> 3;
  const int sunit = (l & 7) ^ (srow & 7);
  for (int mt = 0; mt < 16; ++mt) {
    const int m0 = mt * 64;
#pragma unroll
    for (int c = 0; c < 2; ++c) {
      int s = w * 2 + c;
      gl16(qkv + (size_t)(b * 1024 + m0 + 8 * s + srow) * 2304 + 768 + h * 64 + (sunit << 3),
           (char*)lK + s * 1024);
    }
#pragma unroll
    for (int c = 0; c < 2; ++c) {
      int s = w * 2 + c;
      gl16(vT + (size_t)(bh * 64 + 8 * s + srow) * 1024 + m0 + (sunit << 3),
           (char*)lV + s * 1024);
    }
    __syncthreads();

    // S^T = K Q^T
    f32x4 sacc[2][4];
#pragma unroll
    for (int kk = 0; kk < 2; ++kk) {
      bf16x8 kf[4];
#pragma unroll
      for (int c = 0; c < 4; ++c) {
        int r = 16 * c + l15;
        kf[c] = *(const bf16x8*)((const char*)lK + r * 128 + (((kk * 4 + lg) ^ (r & 7)) << 4));
      }
      __builtin_amdgcn_s_setprio(1);
#pragma unroll
      for (int a = 0; a < 2; ++a)
#pragma unroll
        for (int c = 0; c < 4; ++c)
          sacc[a][c] = __builtin_amdgcn_mfma_f32_16x16x32_bf16(
              kf[c], qf[a][kk], kk == 0 ? zz : sacc[a][c], 0, 0, 0);
      __builtin_amdgcn_s_setprio(0);
    }

    // poly -> packed bf16x4 -> one ds_write_b64 per fragment
#pragma unroll
    for (int a = 0; a < 2; ++a)
#pragma unroll
      for (int c = 0; c < 4; ++c) {
        int q = w * 32 + 16 * a + l15;
        int mb2 = 32 * c + 8 * lg;
        bf16x4 pk;
#pragma unroll
        for (int e = 0; e < 4; ++e) {
          float s = sacc[a][c][e] * 0.125f;
          float p = (pa * s + pb) * s + pc;
          pk[e] = (__bf16)p;
        }
        *(bf16x4*)((char*)lP + q * 128 + (mb2 ^ ((q & 7) << 4))) = pk;
      }

    // O += P @ V
#pragma unroll
    for (int kk = 0; kk < 2; ++kk) {
      bf16x8 vf[4];
#pragma unroll
      for (int nf = 0; nf < 4; ++nf) {
        int d = 16 * nf + l15;
        vf[nf] = *(const bf16x8*)((const char*)lV + d * 128 + (((kk * 4 + lg) ^ (d & 7)) << 4));
      }
      bf16x8 pf[2];
#pragma unroll
      for (int mf = 0; mf < 2; ++mf) {
        int q = w * 32 + 16 * mf + l15;
        pf[mf] = *(const bf16x8*)((const char*)lP + q * 128 + (((kk * 4 + lg) ^ (q & 7)) << 4));
      }
      __builtin_amdgcn_s_setprio(1);
#pragma unroll
      for (int mf = 0; mf < 2; ++mf)
#pragma unroll
        for (int nf = 0; nf < 4; ++nf)
          oacc[mf][nf] = __builtin_amdgcn_mfma_f32_16x16x32_bf16(pf[mf], vf[nf], oacc[mf][nf], 0, 0, 0);
      __builtin_amdgcn_s_setprio(0);
    }
    __syncthreads();
  }

#pragma unroll
  for (int mf = 0; mf < 2; ++mf)
#pragma unroll
    for (int nf = 0; nf < 4; ++nf)
#pragma unroll
      for (int e = 0; e < 4; ++e) {
        int row = q0 + w * 32 + 16 * mf + 4 * lg + e;
        int d = 16 * nf + l15;
        o[(size_t)(b * 1024 + row) * 768 + h * 64 + d] = (__bf16)oacc[mf][nf][e];
      }
}

// ---------------- launch ----------------
extern "C" void kernel_launch(void* const* d_in, const int* in_sizes, int n_in,
                              void* d_out, int out_size, void* d_ws, size_t ws_size,
                              hipStream_t stream) {
  const float* x      = (const float*)d_in[0];  // [16,1024,768]
  const float* w_qkv  = (const float*)d_in[1];  // [2304,768]
  const float* b_qkv  = (const float*)d_in[2];  // [2304]
  const float* w_proj = (const float*)d_in[3];  // [768,768]
  const float* b_proj = (const float*)d_in[4];  // [768]
  const float* poly   = (const float*)d_in[5];  // [3]

  char* ws = (char*)d_ws;
  __bf16* xb     = (__bf16*)(ws);                 // 16384x768   = 25165824 B
  __bf16* wqkvb  = (__bf16*)(ws + 25165824);      // 2304x768    =  3538944 B
  __bf16* wprojb = (__bf16*)(ws + 28704768);      // 768x768     =  1179648 B
  __bf16* qkvb   = (__bf16*)(ws + 29884416);      // 16384x2304  = 75497472 B
  __bf16* vtb    = (__bf16*)(ws + 105381888);     // 192x64x1024 = 25165824 B
  __bf16* ob     = (__bf16*)(ws + 130547712);     // 16384x768   = 25165824 B

  cvtk<<<12582912 / 1024, 256, 0, stream>>>(x, xb, 12582912);
  cvtk<<<1769472 / 1024, 256, 0, stream>>>(w_qkv, wqkvb, 1769472);
  cvtk<<<589824 / 1024, 256, 0, stream>>>(w_proj, wprojb, 589824);

  // QK strips (cols 0..1535): 64 row-tiles x 6 col-tiles = 384 blocks, D^T epilogue
  gemm256k<0, true><<<384, 512, 0, stream>>>(xb, wqkvb, b_qkv, qkvb, nullptr,
                                             768, 6, 48, 0, 2304);
  // V strips (cols 1536..2303): 64 x 3 = 192 blocks, transposed into vtb
  gemm256k<0, false><<<192, 512, 0, stream>>>(xb, wqkvb, b_qkv, nullptr, vtb,
                                              768, 3, 24, 1536, 2304);
  attnk<<<dim3(8, 192), 256, 0, stream>>>(qkvb, vtb, ob, poly);
  // proj: 64 x 3 = 192 blocks, f32 out, D^T epilogue
  gemm256k<1, true><<<192, 512, 0, stream>>>(ob, wprojb, b_proj, d_out, nullptr,
                                             768, 3, 24, 0, 768);
}

// Round 6
// 228.799 us; speedup vs baseline: 4.0405x; 4.0405x over previous
//
#include <hip/hip_runtime.h>
#include <hip/hip_bf16.h>

// PolyAttentionBlock: B=16 N=1024 C=768 H=12 D=64. attn = a*s^2+b*s+c (no softmax).
// cvt -> QKV GEMM (256x128 2-phase, 2 blocks/CU; Q,K->per-head bufs, V->vT) -> attn -> proj.

typedef float  f32x4  __attribute__((ext_vector_type(4)));
typedef __bf16 bf16x8 __attribute__((ext_vector_type(8)));
typedef __bf16 bf16x4 __attribute__((ext_vector_type(4)));

#define AS1 __attribute__((address_space(1)))
#define AS3 __attribute__((address_space(3)))

__device__ __forceinline__ void gl16(const void* g, void* l) {
  __builtin_amdgcn_global_load_lds((const AS1 unsigned int*)g, (AS3 unsigned int*)l, 16, 0, 0);
}

// ---------------- f32 -> bf16 cast ----------------
__global__ __launch_bounds__(256) void cvtk(const float* __restrict__ s,
                                            __bf16* __restrict__ d, int n) {
  int i = (blockIdx.x * 256 + threadIdx.x) * 4;
  if (i >= n) return;
  float4 v = *reinterpret_cast<const float4*>(s + i);
  bf16x4 o = { (__bf16)v.x, (__bf16)v.y, (__bf16)v.z, (__bf16)v.w };
  *reinterpret_cast<bf16x4*>(d + i) = o;
}

// ---------------- 256x128 2-phase GEMM core ----------------
// 512 thr = 8 waves (4M x 2N), wave tile 64x64, BK=32, LDS 48KB dbuf -> 2 blocks/CU.
// LDS: k-major 1KB chunks (16 rows x 32 k); chunk layout [lg][l15][8k] -> ds_read_b128
// of a frag is a contiguous 1KB linear copy pattern (0 conflicts).
// acc[m][n][e]: SWAP -> C[row= wm*64+m*16+l15][col= wn*64+n*16+lg*4+e] (e runs along cols)
//               !SWAP -> C[row= wm*64+m*16+lg*4+e][col= wn*64+n*16+l15] (e runs along rows)
template <bool SWAP>
__device__ __forceinline__ void gemm_core(const __bf16* __restrict__ A,
                                          const __bf16* __restrict__ W, int K,
                                          int row0, int col0, char* lds,
                                          int w, int l, f32x4 (&acc)[4][4]) {
  const int l15 = l & 15, lg = l >> 4;
  const int wm = w >> 1, wn = w & 1;
  // staging source pointers (advance 32 elems per K-tile)
  const __bf16* pa0 = A + (size_t)(row0 + w * 16 + l15) * K + lg * 8;         // A chunks 0..7
  const __bf16* pa1 = A + (size_t)(row0 + 128 + w * 16 + l15) * K + lg * 8;   // A chunks 8..15
  const __bf16* pb  = W + (size_t)(col0 + w * 16 + l15) * K + lg * 8;         // B chunks 0..7
  char* dA0 = lds + w * 1024;           // dbuf stride 24576
  char* dA1 = lds + 8192 + w * 1024;
  char* dB  = lds + 16384 + w * 1024;

  const int NT = K >> 5;  // 24
  // prologue: stage tile 0 into buf0
  gl16(pa0, dA0); gl16(pa1, dA1); gl16(pb, dB);
  asm volatile("s_waitcnt vmcnt(0)" ::: "memory");
  __builtin_amdgcn_s_barrier();
  __builtin_amdgcn_sched_barrier(0);

  for (int t = 0; t < NT; ++t) {
    const int cur = (t & 1) * 24576;
    const int nxt = ((t + 1) & 1) * 24576;
    if (t + 1 < NT) {
      const size_t ko = (size_t)(t + 1) * 32;
      gl16(pa0 + ko, dA0 + nxt); gl16(pa1 + ko, dA1 + nxt); gl16(pb + ko, dB + nxt);
    }
    bf16x8 af[4], bfr[4];
#pragma unroll
    for (int m = 0; m < 4; ++m)
      af[m] = *(const bf16x8*)(lds + cur + (wm * 4 + m) * 1024 + lg * 256 + l15 * 16);
#pragma unroll
    for (int n = 0; n < 4; ++n)
      bfr[n] = *(const bf16x8*)(lds + cur + 16384 + (wn * 4 + n) * 1024 + lg * 256 + l15 * 16);
    __builtin_amdgcn_s_setprio(1);
#pragma unroll
    for (int m = 0; m < 4; ++m)
#pragma unroll
      for (int n = 0; n < 4; ++n) {
        if (SWAP)
          acc[m][n] = __builtin_amdgcn_mfma_f32_16x16x32_bf16(bfr[n], af[m], acc[m][n], 0, 0, 0);
        else
          acc[m][n] = __builtin_amdgcn_mfma_f32_16x16x32_bf16(af[m], bfr[n], acc[m][n], 0, 0, 0);
      }
    __builtin_amdgcn_s_setprio(0);
    asm volatile("s_waitcnt vmcnt(0)" ::: "memory");
    __builtin_amdgcn_s_barrier();
    __builtin_amdgcn_sched_barrier(0);  // fence: next iter's ds_reads must not hoist above
  }
}

// PROJ=0: QKV. cols<768 -> qh[bh][n][64]; <1536 -> kh; else V -> vT[bh][64][1024].
// PROJ=1: proj, f32 packed out.
template <int PROJ>
__global__ __launch_bounds__(512, 4) void gemm2ph(
    const __bf16* __restrict__ A, const __bf16* __restrict__ W,
    const float* __restrict__ bias, void* __restrict__ out0,
    __bf16* __restrict__ kh, __bf16* __restrict__ vt,
    int K, int nby, int chunk, int ldo) {
  __shared__ char lds[49152];
  const int t = threadIdx.x, w = t >> 6, l = t & 63;
  const int l15 = l & 15, lg = l >> 4;
  const int wm = w >> 1, wn = w & 1;

  // bijective XCD-chunked swizzle (grid % 8 == 0), row-major chunks
  const int fid = blockIdx.x;
  const int logical = (fid & 7) * chunk + (fid >> 3);
  const int bx = logical / nby, by = logical % nby;
  const int row0 = bx * 256, col0 = by * 128;

  const f32x4 zz = {0.f, 0.f, 0.f, 0.f};
  f32x4 acc[4][4];
#pragma unroll
  for (int m = 0; m < 4; ++m)
#pragma unroll
    for (int n = 0; n < 4; ++n) acc[m][n] = zz;

  const bool swap = (PROJ == 1) || (col0 < 1536);
  if (swap) gemm_core<true>(A, W, K, row0, col0, lds, w, l, acc);
  else      gemm_core<false>(A, W, K, row0, col0, lds, w, l, acc);

  if (swap) {
    // e runs along cols
    f32x4 bv4[4];
#pragma unroll
    for (int n = 0; n < 4; ++n)
      bv4[n] = *(const f32x4*)(bias + col0 + wn * 64 + n * 16 + lg * 4);
#pragma unroll
    for (int m = 0; m < 4; ++m) {
      const int row = row0 + wm * 64 + m * 16 + l15;
#pragma unroll
      for (int n = 0; n < 4; ++n) {
        const int colb = col0 + wn * 64 + n * 16 + lg * 4;
        if (PROJ == 1) {
          f32x4 v;
#pragma unroll
          for (int e = 0; e < 4; ++e) v[e] = acc[m][n][e] + bv4[n][e];
          *(f32x4*)((float*)out0 + (size_t)row * ldo + colb) = v;
        } else {
          bf16x4 pk;
#pragma unroll
          for (int e = 0; e < 4; ++e) pk[e] = (__bf16)(acc[m][n][e] + bv4[n][e]);
          const int b = row >> 10, nn = row & 1023;
          if (colb < 768) {  // Q -> qh[bh][n][64]
            const int h = colb >> 6, d0 = colb & 63;
            *(bf16x4*)((__bf16*)out0 + (((size_t)(b * 12 + h)) << 16) + nn * 64 + d0) = pk;
          } else {           // K -> kh[bh][n][64]
            const int ck = colb - 768, h = ck >> 6, d0 = ck & 63;
            *(bf16x4*)(kh + (((size_t)(b * 12 + h)) << 16) + nn * 64 + d0) = pk;
          }
        }
      }
    }
  } else {
    // V path: e runs along rows (tokens) -> contiguous nn in vT[bh][64][1024]
    float bv[4];
#pragma unroll
    for (int n = 0; n < 4; ++n) bv[n] = bias[col0 + wn * 64 + n * 16 + l15];
#pragma unroll
    for (int m = 0; m < 4; ++m)
#pragma unroll
      for (int n = 0; n < 4; ++n) {
        const int cv = col0 - 1536 + wn * 64 + n * 16 + l15;
        const int h = cv >> 6, d = cv & 63;
        const int row = row0 + wm * 64 + m * 16 + lg * 4;
        const int b = row >> 10, nn = row & 1023;
        bf16x4 pk;
#pragma unroll
        for (int e = 0; e < 4; ++e) pk[e] = (__bf16)(acc[m][n][e] + bv[n]);
        *(bf16x4*)(vt + (((size_t)(b * 12 + h)) << 16) + (d << 10) + nn) = pk;
      }
  }
}

// ---------------- fused poly attention ----------------
// grid 1536 (XCD-chunked), 256 thr = 4 waves; KVBLK=64, 16 tiles.
// Q,K from per-head bufs qh/kh[bh][1024][64] (128B rows -> coalesced staging).
__global__ __launch_bounds__(256, 3) void attnk(const __bf16* __restrict__ qh,
                                                const __bf16* __restrict__ kh,
                                                const __bf16* __restrict__ vT,
                                                __bf16* __restrict__ o,
                                                const float* __restrict__ poly) {
  __shared__ __bf16 lK[64 * 64];   // 8KB  [m][d=64], 128B rows, XOR-swizzled
  __shared__ __bf16 lV[64 * 64];   // 8KB  [d][m=64], 128B rows, XOR-swizzled
  __shared__ __bf16 lP[128 * 64];  // 16KB [q][m=64]; wave w owns rows w*32..+31
  const int t = threadIdx.x, w = t >> 6, l = t & 63;
  const int l15 = l & 15, lg = l >> 4;

  const int fid = blockIdx.y * 8 + blockIdx.x;       // 0..1535
  const int logical = (fid & 7) * 192 + (fid >> 3);
  const int bh = logical >> 3, q0 = (logical & 7) * 128;
  const float pa = poly[0], pb = poly[1], pc = poly[2];
  const f32x4 zz = {0.f, 0.f, 0.f, 0.f};
  const size_t bhoff = ((size_t)bh) << 16;

  bf16x8 qf[2][2];
#pragma unroll
  for (int a = 0; a < 2; ++a)
#pragma unroll
    for (int kk = 0; kk < 2; ++kk)
      qf[a][kk] = *(const bf16x8*)(qh + bhoff + (q0 + w * 32 + 16 * a + l15) * 64 +
                                   kk * 32 + lg * 8);

  f32x4 oacc[2][4];
#pragma unroll
  for (int mf = 0; mf < 2; ++mf)
#pragma unroll
    for (int n = 0; n < 4; ++n) oacc[mf][n] = zz;

  const int srow = l >> 3;
  const int sunit = (l & 7) ^ (srow & 7);
  for (int mt = 0; mt < 16; ++mt) {
    const int m0 = mt * 64;
#pragma unroll
    for (int c = 0; c < 2; ++c) {
      int s = w * 2 + c;
      gl16(kh + bhoff + (m0 + 8 * s + srow) * 64 + (sunit << 3), (char*)lK + s * 1024);
    }
#pragma unroll
    for (int c = 0; c < 2; ++c) {
      int s = w * 2 + c;
      gl16(vT + bhoff + (8 * s + srow) * 1024 + m0 + (sunit << 3), (char*)lV + s * 1024);
    }
    __syncthreads();

    // S^T = K Q^T
    f32x4 sacc[2][4];
#pragma unroll
    for (int kk = 0; kk < 2; ++kk) {
      bf16x8 kf[4];
#pragma unroll
      for (int c = 0; c < 4; ++c) {
        int r = 16 * c + l15;
        kf[c] = *(const bf16x8*)((const char*)lK + r * 128 + (((kk * 4 + lg) ^ (r & 7)) << 4));
      }
      __builtin_amdgcn_s_setprio(1);
#pragma unroll
      for (int a = 0; a < 2; ++a)
#pragma unroll
        for (int c = 0; c < 4; ++c)
          sacc[a][c] = __builtin_amdgcn_mfma_f32_16x16x32_bf16(
              kf[c], qf[a][kk], kk == 0 ? zz : sacc[a][c], 0, 0, 0);
      __builtin_amdgcn_s_setprio(0);
    }

    // poly -> packed bf16x4 ds_write
#pragma unroll
    for (int a = 0; a < 2; ++a)
#pragma unroll
      for (int c = 0; c < 4; ++c) {
        int q = w * 32 + 16 * a + l15;
        int mb2 = 32 * c + 8 * lg;
        bf16x4 pk;
#pragma unroll
        for (int e = 0; e < 4; ++e) {
          float s = sacc[a][c][e] * 0.125f;
          float p = (pa * s + pb) * s + pc;
          pk[e] = (__bf16)p;
        }
        *(bf16x4*)((char*)lP + q * 128 + (mb2 ^ ((q & 7) << 4))) = pk;
      }

    // O += P @ V
#pragma unroll
    for (int kk = 0; kk < 2; ++kk) {
      bf16x8 vf[4];
#pragma unroll
      for (int nf = 0; nf < 4; ++nf) {
        int d = 16 * nf + l15;
        vf[nf] = *(const bf16x8*)((const char*)lV + d * 128 + (((kk * 4 + lg) ^ (d & 7)) << 4));
      }
      bf16x8 pf[2];
#pragma unroll
      for (int mf = 0; mf < 2; ++mf) {
        int q = w * 32 + 16 * mf + l15;
        pf[mf] = *(const bf16x8*)((const char*)lP + q * 128 + (((kk * 4 + lg) ^ (q & 7)) << 4));
      }
      __builtin_amdgcn_s_setprio(1);
#pragma unroll
      for (int mf = 0; mf < 2; ++mf)
#pragma unroll
        for (int nf = 0; nf < 4; ++nf)
          oacc[mf][nf] = __builtin_amdgcn_mfma_f32_16x16x32_bf16(pf[mf], vf[nf], oacc[mf][nf], 0, 0, 0);
      __builtin_amdgcn_s_setprio(0);
    }
    __syncthreads();
  }

  const int b = bh / 12, h = bh - b * 12;
#pragma unroll
  for (int mf = 0; mf < 2; ++mf)
#pragma unroll
    for (int nf = 0; nf < 4; ++nf)
#pragma unroll
      for (int e = 0; e < 4; ++e) {
        int row = q0 + w * 32 + 16 * mf + 4 * lg + e;
        int d = 16 * nf + l15;
        o[(size_t)(b * 1024 + row) * 768 + h * 64 + d] = (__bf16)oacc[mf][nf][e];
      }
}

// ---------------- launch ----------------
extern "C" void kernel_launch(void* const* d_in, const int* in_sizes, int n_in,
                              void* d_out, int out_size, void* d_ws, size_t ws_size,
                              hipStream_t stream) {
  const float* x      = (const float*)d_in[0];
  const float* w_qkv  = (const float*)d_in[1];
  const float* b_qkv  = (const float*)d_in[2];
  const float* w_proj = (const float*)d_in[3];
  const float* b_proj = (const float*)d_in[4];
  const float* poly   = (const float*)d_in[5];

  char* ws = (char*)d_ws;
  __bf16* xb     = (__bf16*)(ws);                 // 16384x768   = 25165824 B
  __bf16* wqkvb  = (__bf16*)(ws + 25165824);      // 2304x768    =  3538944 B
  __bf16* wprojb = (__bf16*)(ws + 28704768);      // 768x768     =  1179648 B
  __bf16* qh     = (__bf16*)(ws + 29884416);      // 192x1024x64 = 25165824 B
  __bf16* kh     = (__bf16*)(ws + 55050240);      // 192x1024x64 = 25165824 B
  __bf16* vtb    = (__bf16*)(ws + 80216064);      // 192x64x1024 = 25165824 B
  __bf16* ob     = (__bf16*)(ws + 105381888);     // 16384x768   = 25165824 B

  cvtk<<<12582912 / 1024, 256, 0, stream>>>(x, xb, 12582912);
  cvtk<<<1769472 / 1024, 256, 0, stream>>>(w_qkv, wqkvb, 1769472);
  cvtk<<<589824 / 1024, 256, 0, stream>>>(w_proj, wprojb, 589824);

  // QKV: 64 rowtiles x 18 coltiles = 1152 blocks (chunk 144)
  gemm2ph<0><<<1152, 512, 0, stream>>>(xb, wqkvb, b_qkv, qh, kh, vtb, 768, 18, 144, 0);
  attnk<<<dim3(8, 192), 256, 0, stream>>>(qh, kh, vtb, ob, poly);
  // proj: 64 x 6 = 384 blocks (chunk 48), f32 out
  gemm2ph<1><<<384, 512, 0, stream>>>(ob, wprojb, b_proj, d_out, nullptr, nullptr, 768, 6, 48, 768);
}